// Round 3
// baseline (556.538 us; speedup 1.0000x reference)
//
#include <hip/hip_runtime.h>
#include <hip/hip_bf16.h>
#include <stdint.h>

// Problem dims (SMC transformer, noise=False => causal self-attention)
#define BB 8
#define SS 2048
#define TT (BB*SS)       // 16384 tokens total (P=1)
#define DD 512
#define DFFX 2048

static __device__ const float SQRTD  = 22.627416997969522f;   // sqrt(512)
static __device__ const float INVSQD = 0.04419417382415922f;  // 1/sqrt(512)

typedef __attribute__((ext_vector_type(4))) float  f32x4_t;
typedef __attribute__((ext_vector_type(8))) __bf16 bf16x8_t;
typedef __attribute__((ext_vector_type(4))) __bf16 bf16x4_t;

// MFMA 16x16x32 bf16 operand layout (gfx950), HW-verified in rounds 1-2:
//   A: lane l, elem e -> A[l&15][4*(l>>4) + (e&3) + 16*(e>>2)]
//   B: lane l, elem e -> B[4*(l>>4) + (e&3) + 16*(e>>2)][l&15]
//   D: lane l, reg  r -> D[4*(l>>4) + r][l&15]
static __device__ __forceinline__ bf16x8_t mk_frag(bf16x4_t lo, bf16x4_t hi) {
  return __builtin_shufflevector(lo, hi, 0, 1, 2, 3, 4, 5, 6, 7);
}

// async global->LDS, 16B per lane, dest = uniform base + lane*16
typedef __attribute__((address_space(1))) const unsigned int g_u32;
typedef __attribute__((address_space(3))) unsigned int lds_u32;
static __device__ __forceinline__ void gld16(const void* g, void* l) {
  __builtin_amdgcn_global_load_lds((g_u32*)g, (lds_u32*)l, 16, 0, 0);
}

// ---------------- weight transpose + convert: dst[C][R] (bf16) = src[R][C] (f32)
__global__ __launch_bounds__(256) void transpose_conv_f32(
    const float* __restrict__ src, __bf16* __restrict__ dst, int R, int C) {
  __shared__ float tile[32][33];
  int c0 = blockIdx.x * 32, r0 = blockIdx.y * 32;
  int tx = threadIdx.x & 31, ty = threadIdx.x >> 5;
#pragma unroll
  for (int i = 0; i < 4; i++)
    tile[ty + 8*i][tx] = src[(size_t)(r0 + ty + 8*i) * C + c0 + tx];
  __syncthreads();
#pragma unroll
  for (int i = 0; i < 4; i++)
    dst[(size_t)(c0 + ty + 8*i) * R + r0 + tx] = (__bf16)tile[tx][ty + 8*i];
}

// ---------------- per-batch bf16 transpose: dst[z][C][R] = src[z][R][C]
__global__ __launch_bounds__(256) void transpose_bf16(
    const __bf16* __restrict__ src_, __bf16* __restrict__ dst_, int R, int C) {
  __shared__ __bf16 tile[32][34];
  const __bf16* src = src_ + (size_t)blockIdx.z * R * C;
  __bf16* dst = dst_ + (size_t)blockIdx.z * R * C;
  int c0 = blockIdx.x * 32, r0 = blockIdx.y * 32;
  int tx = threadIdx.x & 31, ty = threadIdx.x >> 5;
#pragma unroll
  for (int i = 0; i < 4; i++)
    tile[ty + 8*i][tx] = src[(size_t)(r0 + ty + 8*i) * C + c0 + tx];
  __syncthreads();
#pragma unroll
  for (int i = 0; i < 4; i++)
    dst[(size_t)(c0 + ty + 8*i) * R + r0 + tx] = tile[tx][ty + 8*i];
}

// ---------------- x = (inp @ Wp + bp) * sqrt(D), K=16, out bf16
__global__ __launch_bounds__(256) void projx_kernel(
    const float* __restrict__ inp, const float* __restrict__ Wp,
    const float* __restrict__ bp, __bf16* __restrict__ xb) {
  __shared__ float wps[16][512];
  for (int i = threadIdx.x; i < 16 * 512; i += 256) wps[i >> 9][i & 511] = Wp[i];
  __syncthreads();
  const int t = blockIdx.x * 4 + (threadIdx.x >> 6);
  const int li = threadIdx.x & 63;
  float iv[16];
#pragma unroll
  for (int r = 0; r < 16; r++) iv[r] = inp[(size_t)t * 16 + r];
  float acc[8];
#pragma unroll
  for (int j = 0; j < 8; j++) acc[j] = 0.f;
#pragma unroll
  for (int r = 0; r < 16; r++) {
#pragma unroll
    for (int j = 0; j < 8; j++) acc[j] += iv[r] * wps[r][li + 64 * j];
  }
#pragma unroll
  for (int j = 0; j < 8; j++) {
    int c = li + 64 * j;
    xb[(size_t)t * DD + c] = (__bf16)((acc[j] + bp[c]) * SQRTD);
  }
}

// ---------------- 128x128-tile MFMA GEMM: C[M][N] = A[M][K] @ Bt[N][K]^T
// Staging via global_load_lds(16B) into LINEAR LDS [128][32] bf16 with an
// XOR chunk swizzle applied on the global SOURCE address and the ds_read
// addresses (same involution; rule #21): 16B chunk p at row r holds logical
// chunk p ^ ((r>>1)&3). Bank-quad = 4*(r&1) + (chunk^((r>>1)&3)) -> 8
// consecutive rows hit 8 distinct quads -> only 2-way aliasing (free).
// CTRI: skip blocks with n0 > m0+127 (causal score triangle).
// CAUSAL: k-loop ends at m0+128 (PV).  RELU: relu(acc+bias).  RES: += Res.
// SCALE: acc *= 1/sqrt(D) before bias.
template <bool CTRI, bool CAUSAL, bool RELU, bool RES, bool SCALE>
__global__ __launch_bounds__(256) void gemm128(
    const __bf16* __restrict__ A, const __bf16* __restrict__ Bt,
    const float* __restrict__ bias, const __bf16* __restrict__ Res,
    __bf16* __restrict__ Cb, float* __restrict__ Cf,
    int N, int K, size_t aBatch, size_t bBatch, size_t cBatch) {
  const int n0 = blockIdx.x * 128, m0 = blockIdx.y * 128;
  if (CTRI && n0 > m0 + 127) return;
  __shared__ __align__(16) __bf16 As[128 * 32];
  __shared__ __align__(16) __bf16 Bs[128 * 32];
  const int tid = threadIdx.x, lane = tid & 63, wave = tid >> 6;
  const int l15 = lane & 15, g = lane >> 4;
  const int wr = wave >> 1, wc = wave & 1;

  // ---- staging decode: lane's LDS slot is wave*2048 + q*1024 + lane*16 bytes.
  // row = wave*32 + q*16 + (lane>>2); physical chunk = lane&3;
  // source logical chunk = (lane&3) ^ ((row>>1)&3)  (XOR involution)
  const int srow0 = wave * 32 + (lane >> 2);
  const int srow1 = srow0 + 16;
  const int sc0 = (((lane & 3) ^ ((srow0 >> 1) & 3)) << 4);  // byte col in 64B row
  const int sc1 = (((lane & 3) ^ ((srow1 >> 1) & 3)) << 4);
  const size_t aOff = (size_t)blockIdx.z * aBatch;
  const size_t bOff = (size_t)blockIdx.z * bBatch;
  const size_t cOff = (size_t)blockIdx.z * cBatch;
  const char* ga0 = (const char*)(A + aOff + (size_t)(m0 + srow0) * K) + sc0;
  const char* ga1 = (const char*)(A + aOff + (size_t)(m0 + srow1) * K) + sc1;
  const char* gb0 = (const char*)(Bt + bOff + (size_t)(n0 + srow0) * K) + sc0;
  const char* gb1 = (const char*)(Bt + bOff + (size_t)(n0 + srow1) * K) + sc1;
  char* lA = (char*)As + wave * 2048;
  char* lB = (char*)Bs + wave * 2048;

  // ---- frag-read addressing (byte offsets into linear+swizzled LDS).
  // A-frag i, this lane: row r = wr*64 + i*16 + l15; lo chunk = g>>1,
  // hi chunk = (g>>1)|2; physical = logical ^ ((r>>1)&3) = logical ^ ((l15>>1)&3)
  // (i*16 and wr*64 don't affect bits 1-2 of r). hi addr = lo addr ^ 32.
  const int sxr = (l15 >> 1) & 3;
  const int plo = (g >> 1) ^ sxr;
  const int aof0 = (wr * 64 + l15) * 64 + plo * 16 + (g & 1) * 8;
  const int bof0 = (wc * 64 + l15) * 64 + plo * 16 + (g & 1) * 8;
  const char* AsB = (const char*)As;
  const char* BsB = (const char*)Bs;

  f32x4_t acc[4][4];
#pragma unroll
  for (int i = 0; i < 4; i++)
#pragma unroll
    for (int j = 0; j < 4; j++) acc[i][j] = (f32x4_t){0.f, 0.f, 0.f, 0.f};

  const int kend = CAUSAL ? (m0 + 128) : K;
  for (int k0 = 0; k0 < kend; k0 += 32) {
    const size_t kb = (size_t)k0 * 2;
    gld16(ga0 + kb, lA);
    gld16(ga1 + kb, lA + 1024);
    gld16(gb0 + kb, lB);
    gld16(gb1 + kb, lB + 1024);
    __syncthreads();   // vmcnt(0) drain + barrier: tile visible
    bf16x8_t af[4], bfr[4];
#pragma unroll
    for (int i = 0; i < 4; i++) {
      const int ao = aof0 + i * 1024;
      af[i] = mk_frag(*(const bf16x4_t*)(AsB + ao),
                      *(const bf16x4_t*)(AsB + (ao ^ 32)));
      const int bo = bof0 + i * 1024;
      bfr[i] = mk_frag(*(const bf16x4_t*)(BsB + bo),
                       *(const bf16x4_t*)(BsB + (bo ^ 32)));
    }
#pragma unroll
    for (int i = 0; i < 4; i++)
#pragma unroll
      for (int j = 0; j < 4; j++)
        acc[i][j] = __builtin_amdgcn_mfma_f32_16x16x32_bf16(af[i], bfr[j], acc[i][j], 0, 0, 0);
    __syncthreads();   // all reads done before next stage overwrites
  }
#pragma unroll
  for (int i = 0; i < 4; i++) {
#pragma unroll
    for (int j = 0; j < 4; j++) {
      const int col = n0 + wc * 64 + j * 16 + l15;
      const float bv = bias ? bias[col] : 0.f;
#pragma unroll
      for (int r = 0; r < 4; r++) {
        const int row = m0 + wr * 64 + i * 16 + g * 4 + r;
        float v = acc[i][j][r];
        if (SCALE) v *= INVSQD;
        v += bv;
        if (RELU) v = fmaxf(v, 0.f);
        if (RES) v += (float)Res[(size_t)row * N + col];
        const size_t cidx = cOff + (size_t)row * N + col;
        if (Cb) Cb[cidx] = (__bf16)v;
        if (Cf) Cf[cidx] = v;
      }
    }
  }
}

// ---------------- row softmax, in place on fp32 scores (lower-tri valid),
// writes normalized fp32 probs (exact zeros above diagonal) + bf16 copy.
__global__ __launch_bounds__(256) void softmax_kernel(
    float* __restrict__ att, __bf16* __restrict__ pb) {
  const int t = blockIdx.x * 4 + (threadIdx.x >> 6);   // global row (b*2048+q)
  const int gq = t & (SS - 1);                         // query index in batch
  const int lane = threadIdx.x & 63;
  float* row = att + (size_t)t * SS;
  __bf16* prow = pb + (size_t)t * SS;
  const int nch = (gq >> 9) + 1;   // 512-wide chunks containing valid cols
  float x[32];
  float m = -1e30f;
#pragma unroll
  for (int ch = 0; ch < 4; ch++) {
    float* xp = &x[ch * 8];
    if (ch < nch) {
      const int c0 = ch * 512 + lane * 8;
      float4 v0 = *(const float4*)(row + c0);
      float4 v1 = *(const float4*)(row + c0 + 4);
      xp[0]=v0.x; xp[1]=v0.y; xp[2]=v0.z; xp[3]=v0.w;
      xp[4]=v1.x; xp[5]=v1.y; xp[6]=v1.z; xp[7]=v1.w;
#pragma unroll
      for (int j = 0; j < 8; j++) {
        xp[j] = (c0 + j <= gq) ? xp[j] : -1e30f;  // select: immune to garbage
        m = fmaxf(m, xp[j]);
      }
    } else {
#pragma unroll
      for (int j = 0; j < 8; j++) xp[j] = -1e30f;
    }
  }
#pragma unroll
  for (int off = 1; off < 64; off <<= 1) m = fmaxf(m, __shfl_xor(m, off, 64));
  float s = 0.f;
#pragma unroll
  for (int i = 0; i < 32; i++) { x[i] = __expf(x[i] - m); s += x[i]; }
#pragma unroll
  for (int off = 1; off < 64; off <<= 1) s += __shfl_xor(s, off, 64);
  const float inv = 1.f / s;
#pragma unroll
  for (int ch = 0; ch < 4; ch++) {
    const int c0 = ch * 512 + lane * 8;
    float o[8];
    bf16x8_t ov;
#pragma unroll
    for (int j = 0; j < 8; j++) {
      const float pv = x[ch * 8 + j] * inv;  // masked entries exactly 0
      o[j] = pv;
      ov[j] = (__bf16)pv;
    }
    float4 f0, f1;
    f0.x = o[0]; f0.y = o[1]; f0.z = o[2]; f0.w = o[3];
    f1.x = o[4]; f1.y = o[5]; f1.z = o[6]; f1.w = o[7];
    *(float4*)(row + c0) = f0;
    *(float4*)(row + c0 + 4) = f1;
    *(bf16x8_t*)(prow + c0) = ov;
  }
}

// ---------------- LayerNorm over D=512 (population var, eps inside sqrt)
__global__ __launch_bounds__(256) void ln_kernel(
    const __bf16* __restrict__ X, const float* __restrict__ gam,
    const float* __restrict__ bet, __bf16* __restrict__ Ob, float* __restrict__ Of) {
  const int t = blockIdx.x * 4 + (threadIdx.x >> 6);
  const int lane = threadIdx.x & 63;
  const int d0 = lane * 8;
  bf16x8_t xv = *(const bf16x8_t*)(X + (size_t)t * DD + d0);
  float x[8];
#pragma unroll
  for (int j = 0; j < 8; j++) x[j] = (float)xv[j];
  float s = 0.f, sq = 0.f;
#pragma unroll
  for (int j = 0; j < 8; j++) { s += x[j]; sq += x[j] * x[j]; }
#pragma unroll
  for (int off = 1; off < 64; off <<= 1) {
    s += __shfl_xor(s, off, 64);
    sq += __shfl_xor(sq, off, 64);
  }
  const float mean = s * (1.f / 512.f);
  const float var = sq * (1.f / 512.f) - mean * mean;
  const float rstd = rsqrtf(var + 1e-6f);
  float4 g0 = *(const float4*)(gam + d0), g1v = *(const float4*)(gam + d0 + 4);
  float4 b0 = *(const float4*)(bet + d0), b1v = *(const float4*)(bet + d0 + 4);
  float gg[8] = {g0.x, g0.y, g0.z, g0.w, g1v.x, g1v.y, g1v.z, g1v.w};
  float bb2[8] = {b0.x, b0.y, b0.z, b0.w, b1v.x, b1v.y, b1v.z, b1v.w};
  float o[8];
#pragma unroll
  for (int j = 0; j < 8; j++) o[j] = (x[j] - mean) * rstd * gg[j] + bb2[j];
  if (Ob) {
    bf16x8_t ov;
#pragma unroll
    for (int j = 0; j < 8; j++) ov[j] = (__bf16)o[j];
    *(bf16x8_t*)(Ob + (size_t)t * DD + d0) = ov;
  }
  if (Of) {
    float4 f0; f0.x = o[0]; f0.y = o[1]; f0.z = o[2]; f0.w = o[3];
    float4 f1; f1.x = o[4]; f1.y = o[5]; f1.z = o[6]; f1.w = o[7];
    *(float4*)(Of + (size_t)t * DD + d0) = f0;
    *(float4*)(Of + (size_t)t * DD + d0 + 4) = f1;
  }
}

// ---------------- pred = r @ Wfin + bfin (K=512, N=16), written to both pred slots
__global__ __launch_bounds__(256) void final_kernel(
    const float* __restrict__ Rm, const float* __restrict__ Wfin,
    const float* __restrict__ bfin, float* __restrict__ P1, float* __restrict__ P2) {
  __shared__ float wfs[512][17];
  for (int i = threadIdx.x; i < 512 * 16; i += 256) wfs[i >> 4][i & 15] = Wfin[i];
  __syncthreads();
  const int tl = threadIdx.x >> 4, n = threadIdx.x & 15;
  const int t = blockIdx.x * 16 + tl;
  const float* rp = Rm + (size_t)t * DD;
  float acc = 0.f;
#pragma unroll 4
  for (int k = 0; k < 512; k += 4) {
    float4 rv = *(const float4*)(rp + k);
    acc += rv.x * wfs[k][n] + rv.y * wfs[k + 1][n] + rv.z * wfs[k + 2][n] + rv.w * wfs[k + 3][n];
  }
  const float v = acc + bfin[n];
  P1[(size_t)t * 16 + n] = v;
  P2[(size_t)t * 16 + n] = v;
}

extern "C" void kernel_launch(void* const* d_in, const int* in_sizes, int n_in,
                              void* d_out, int out_size, void* d_ws, size_t ws_size,
                              hipStream_t stream) {
  const float* inp  = (const float*)d_in[0];
  const float* Wp   = (const float*)d_in[2];
  const float* bp   = (const float*)d_in[3];
  const float* Wq   = (const float*)d_in[4];
  const float* bq   = (const float*)d_in[5];
  const float* Wk   = (const float*)d_in[6];
  const float* bk   = (const float*)d_in[7];
  const float* Wv   = (const float*)d_in[8];
  const float* bv   = (const float*)d_in[9];
  const float* Wo   = (const float*)d_in[10];
  const float* bo   = (const float*)d_in[11];
  const float* g1   = (const float*)d_in[12];
  const float* be1  = (const float*)d_in[13];
  const float* g2   = (const float*)d_in[14];
  const float* be2  = (const float*)d_in[15];
  const float* Wf1  = (const float*)d_in[16];
  const float* bf1  = (const float*)d_in[17];
  const float* Wf2  = (const float*)d_in[18];
  const float* bf2  = (const float*)d_in[19];
  const float* Wfin = (const float*)d_in[20];
  const float* bfin = (const float*)d_in[21];
  (void)in_sizes; (void)n_in; (void)out_size; (void)ws_size;

  float* out = (float*)d_out;
  float* o_pred1 = out;                    // (B,P,S,16)
  float* o_pred2 = out + 262144;
  float* o_k     = out + 524288;           // (B,P,S,512)
  float* o_v     = out + 8912896;
  float* o_r     = out + 17301504;
  float* o_att   = out + 25690112;         // (B,P,S,S)

  // workspace carve-up (~208 MB)
  char* base = (char*)d_ws;
  size_t off = 0;
  auto take = [&](size_t n) -> __bf16* {
    __bf16* p = (__bf16*)(base + off);
    off += (n * sizeof(__bf16) + 255) & ~(size_t)255;
    return p;
  };
  __bf16* Wq_t  = take((size_t)DD * DD);
  __bf16* Wk_t  = take((size_t)DD * DD);
  __bf16* Wv_t  = take((size_t)DD * DD);
  __bf16* Wo_t  = take((size_t)DD * DD);
  __bf16* Wf1_t = take((size_t)DD * DFFX);
  __bf16* Wf2_t = take((size_t)DD * DFFX);
  __bf16* xb    = take((size_t)TT * DD);
  __bf16* qbuf  = take((size_t)TT * DD);
  __bf16* kbuf  = take((size_t)TT * DD);
  __bf16* vbuf  = take((size_t)TT * DD);
  __bf16* zb    = take((size_t)TT * DD);
  __bf16* h1b   = take((size_t)TT * DD);
  __bf16* lninb = take((size_t)TT * DD);
  __bf16* ffb   = take((size_t)TT * DFFX);
  __bf16* vt    = take((size_t)TT * DD);
  __bf16* pb    = ffb;  // bf16 probs alias FFN scratch (same element count;
                        // pb dead before FFN1 writes ffb)

  // weights -> bf16 transposed [N][K]
  transpose_conv_f32<<<dim3(16, 16), 256, 0, stream>>>(Wq, Wq_t, DD, DD);
  transpose_conv_f32<<<dim3(16, 16), 256, 0, stream>>>(Wk, Wk_t, DD, DD);
  transpose_conv_f32<<<dim3(16, 16), 256, 0, stream>>>(Wv, Wv_t, DD, DD);
  transpose_conv_f32<<<dim3(16, 16), 256, 0, stream>>>(Wo, Wo_t, DD, DD);
  transpose_conv_f32<<<dim3(64, 16), 256, 0, stream>>>(Wf1, Wf1_t, DD, DFFX);
  transpose_conv_f32<<<dim3(16, 64), 256, 0, stream>>>(Wf2, Wf2_t, DFFX, DD);

  // x projection
  projx_kernel<<<dim3(TT / 4), 256, 0, stream>>>(inp, Wp, bp, xb);

  // q,k,v (k,v also to fp32 outputs)
  gemm128<false, false, false, false, false><<<dim3(4, 128, 1), 256, 0, stream>>>(
      xb, Wq_t, bq, nullptr, qbuf, nullptr, DD, DD, 0, 0, 0);
  gemm128<false, false, false, false, false><<<dim3(4, 128, 1), 256, 0, stream>>>(
      xb, Wk_t, bk, nullptr, kbuf, o_k, DD, DD, 0, 0, 0);
  gemm128<false, false, false, false, false><<<dim3(4, 128, 1), 256, 0, stream>>>(
      xb, Wv_t, bv, nullptr, vbuf, o_v, DD, DD, 0, 0, 0);

  // scores = q @ k^T / sqrt(d) -> fp32 into o_att (lower-triangle blocks only)
  gemm128<true, false, false, false, true><<<dim3(16, 16, BB), 256, 0, stream>>>(
      qbuf, kbuf, nullptr, nullptr, nullptr, o_att, SS, DD,
      (size_t)SS * DD, (size_t)SS * DD, (size_t)SS * SS);

  // v^T per batch (B-operand for PV)
  transpose_bf16<<<dim3(16, 64, BB), 256, 0, stream>>>(vbuf, vt, SS, DD);

  // softmax in place on o_att (fp32 probs, zeros above diag) + bf16 probs -> pb
  softmax_kernel<<<dim3(TT / 4), 256, 0, stream>>>(o_att, pb);

  // z = attn @ v (bf16 probs, causal k-tile skip)
  gemm128<false, true, false, false, false><<<dim3(4, 16, BB), 256, 0, stream>>>(
      pb, vt, nullptr, nullptr, zb, nullptr, DD, SS,
      (size_t)SS * SS, (size_t)DD * SS, (size_t)SS * DD);

  // O-proj + residual x, LN1
  gemm128<false, false, false, true, false><<<dim3(4, 128, 1), 256, 0, stream>>>(
      zb, Wo_t, bo, xb, lninb, nullptr, DD, DD, 0, 0, 0);
  ln_kernel<<<dim3(TT / 4), 256, 0, stream>>>(lninb, g1, be1, h1b, nullptr);

  // FFN (FFN1 overwrites ffb/pb — PV already done)
  gemm128<false, false, true, false, false><<<dim3(16, 128, 1), 256, 0, stream>>>(
      h1b, Wf1_t, bf1, nullptr, ffb, nullptr, DFFX, DD, 0, 0, 0);
  gemm128<false, false, false, true, false><<<dim3(4, 128, 1), 256, 0, stream>>>(
      ffb, Wf2_t, bf2, h1b, lninb, nullptr, DD, DFFX, 0, 0, 0);

  // LN2 -> r (fp32 output), final projection -> pred (written twice)
  ln_kernel<<<dim3(TT / 4), 256, 0, stream>>>(lninb, g2, be2, nullptr, o_r);
  final_kernel<<<dim3(TT / 16), 256, 0, stream>>>(o_r, Wfin, bfin, o_pred1, o_pred2);
}

// Round 4
// 532.412 us; speedup vs baseline: 1.0453x; 1.0453x over previous
//
#include <hip/hip_runtime.h>
#include <hip/hip_bf16.h>
#include <stdint.h>

// Problem dims (SMC transformer, noise=False => causal self-attention)
#define BB 8
#define SS 2048
#define TT (BB*SS)       // 16384 tokens total (P=1)
#define DD 512
#define DFFX 2048

static __device__ const float SQRTD  = 22.627416997969522f;   // sqrt(512)
static __device__ const float INVSQD = 0.04419417382415922f;  // 1/sqrt(512)

typedef __attribute__((ext_vector_type(4))) float  f32x4_t;
typedef __attribute__((ext_vector_type(8))) __bf16 bf16x8_t;
typedef __attribute__((ext_vector_type(4))) __bf16 bf16x4_t;

// MFMA 16x16x32 bf16 operand layout (gfx950), HW-verified rounds 1-3:
//   A: lane l, elem e -> A[l&15][4*(l>>4) + (e&3) + 16*(e>>2)]
//   B: lane l, elem e -> B[4*(l>>4) + (e&3) + 16*(e>>2)][l&15]
//   D: lane l, reg  r -> D[4*(l>>4) + r][l&15]
static __device__ __forceinline__ bf16x8_t mk_frag(bf16x4_t lo, bf16x4_t hi) {
  return __builtin_shufflevector(lo, hi, 0, 1, 2, 3, 4, 5, 6, 7);
}

// async global->LDS, 16B per lane, dest = uniform base + lane*16
typedef __attribute__((address_space(1))) const unsigned int g_u32;
typedef __attribute__((address_space(3))) unsigned int lds_u32;
static __device__ __forceinline__ void gld16(const void* g, void* l) {
  __builtin_amdgcn_global_load_lds((g_u32*)g, (lds_u32*)l, 16, 0, 0);
}

// ---------------- weight transpose + convert: dst[C][R] (bf16) = src[R][C] (f32)
__global__ __launch_bounds__(256) void transpose_conv_f32(
    const float* __restrict__ src, __bf16* __restrict__ dst, int R, int C) {
  __shared__ float tile[32][33];
  int c0 = blockIdx.x * 32, r0 = blockIdx.y * 32;
  int tx = threadIdx.x & 31, ty = threadIdx.x >> 5;
#pragma unroll
  for (int i = 0; i < 4; i++)
    tile[ty + 8*i][tx] = src[(size_t)(r0 + ty + 8*i) * C + c0 + tx];
  __syncthreads();
#pragma unroll
  for (int i = 0; i < 4; i++)
    dst[(size_t)(c0 + ty + 8*i) * R + r0 + tx] = (__bf16)tile[tx][ty + 8*i];
}

// ---------------- per-batch bf16 transpose: dst[z][C][R] = src[z][R][C]
__global__ __launch_bounds__(256) void transpose_bf16(
    const __bf16* __restrict__ src_, __bf16* __restrict__ dst_, int R, int C) {
  __shared__ __bf16 tile[32][34];
  const __bf16* src = src_ + (size_t)blockIdx.z * R * C;
  __bf16* dst = dst_ + (size_t)blockIdx.z * R * C;
  int c0 = blockIdx.x * 32, r0 = blockIdx.y * 32;
  int tx = threadIdx.x & 31, ty = threadIdx.x >> 5;
#pragma unroll
  for (int i = 0; i < 4; i++)
    tile[ty + 8*i][tx] = src[(size_t)(r0 + ty + 8*i) * C + c0 + tx];
  __syncthreads();
#pragma unroll
  for (int i = 0; i < 4; i++)
    dst[(size_t)(c0 + ty + 8*i) * R + r0 + tx] = tile[tx][ty + 8*i];
}

// ---------------- x = (inp @ Wp + bp) * sqrt(D), K=16, out bf16
__global__ __launch_bounds__(256) void projx_kernel(
    const float* __restrict__ inp, const float* __restrict__ Wp,
    const float* __restrict__ bp, __bf16* __restrict__ xb) {
  __shared__ float wps[16][512];
  for (int i = threadIdx.x; i < 16 * 512; i += 256) wps[i >> 9][i & 511] = Wp[i];
  __syncthreads();
  const int t = blockIdx.x * 4 + (threadIdx.x >> 6);
  const int li = threadIdx.x & 63;
  float iv[16];
#pragma unroll
  for (int r = 0; r < 16; r++) iv[r] = inp[(size_t)t * 16 + r];
  float acc[8];
#pragma unroll
  for (int j = 0; j < 8; j++) acc[j] = 0.f;
#pragma unroll
  for (int r = 0; r < 16; r++) {
#pragma unroll
    for (int j = 0; j < 8; j++) acc[j] += iv[r] * wps[r][li + 64 * j];
  }
#pragma unroll
  for (int j = 0; j < 8; j++) {
    int c = li + 64 * j;
    xb[(size_t)t * DD + c] = (__bf16)((acc[j] + bp[c]) * SQRTD);
  }
}

// ---------------- 128x128-tile MFMA GEMM, 2-phase double-buffered (T3 minimal):
// STAGE(t+1) issued BEFORE COMPUTE(t); one __syncthreads (vmcnt0+barrier) per
// K-step, so global-load latency hides under the 16-MFMA compute phase.
// Staging via global_load_lds(16B) into linear LDS with XOR chunk swizzle on
// the global SOURCE and the ds_read addresses (both-sides involution, rule #21).
// CTRI: skip blocks with n0 > m0+127.  CAUSAL: k-loop ends at m0+128 (PV).
// RELU: relu(acc+bias).  RES: += Res.  SCALE: acc *= 1/sqrt(D).
// QKV3: N=1536 fused q/k/v; output segment sub = col>>9 (block-uniform) routes
// to {Cb|Cb2+Cf2|Cb3+Cf3} with bias {bias|bias2|bias3}, ldc=512.
template <bool CTRI, bool CAUSAL, bool RELU, bool RES, bool SCALE, bool QKV3>
__global__ __launch_bounds__(256) void gemm128(
    const __bf16* __restrict__ A, const __bf16* __restrict__ Bt,
    const float* __restrict__ bias, const float* __restrict__ bias2,
    const float* __restrict__ bias3, const __bf16* __restrict__ Res,
    __bf16* __restrict__ Cb, float* __restrict__ Cf,
    __bf16* __restrict__ Cb2, float* __restrict__ Cf2,
    __bf16* __restrict__ Cb3, float* __restrict__ Cf3,
    int N, int K, size_t aBatch, size_t bBatch, size_t cBatch) {
  const int n0 = blockIdx.x * 128, m0 = blockIdx.y * 128;
  if (CTRI && n0 > m0 + 127) return;
  __shared__ __align__(16) __bf16 As[2 * 128 * 32];   // 2 x 8 KB
  __shared__ __align__(16) __bf16 Bs[2 * 128 * 32];
  const int tid = threadIdx.x, lane = tid & 63, wave = tid >> 6;
  const int l15 = lane & 15, g = lane >> 4;
  const int wr = wave >> 1, wc = wave & 1;

  // ---- staging decode: lane's LDS slot = buf*8192 + wave*2048 + lane*16 B.
  // row = wave*32 + q*16 + (lane>>2); physical chunk = lane&3;
  // source logical chunk = (lane&3) ^ ((row>>1)&3)  (XOR involution)
  const int srow0 = wave * 32 + (lane >> 2);
  const int srow1 = srow0 + 16;
  const int sc0 = (((lane & 3) ^ ((srow0 >> 1) & 3)) << 4);
  const int sc1 = (((lane & 3) ^ ((srow1 >> 1) & 3)) << 4);
  const size_t aOff = (size_t)blockIdx.z * aBatch;
  const size_t bOff = (size_t)blockIdx.z * bBatch;
  const size_t cOff = (size_t)blockIdx.z * cBatch;
  const char* ga0 = (const char*)(A + aOff + (size_t)(m0 + srow0) * K) + sc0;
  const char* ga1 = (const char*)(A + aOff + (size_t)(m0 + srow1) * K) + sc1;
  const char* gb0 = (const char*)(Bt + bOff + (size_t)(n0 + srow0) * K) + sc0;
  const char* gb1 = (const char*)(Bt + bOff + (size_t)(n0 + srow1) * K) + sc1;

  // ---- frag-read byte offsets (linear+swizzled LDS):
  // physical chunk = logical ^ ((l15>>1)&3); hi half = lo addr ^ 32.
  const int plo = (g >> 1) ^ ((l15 >> 1) & 3);
  const int aof0 = (wr * 64 + l15) * 64 + plo * 16 + (g & 1) * 8;
  const int bof0 = (wc * 64 + l15) * 64 + plo * 16 + (g & 1) * 8;

  f32x4_t acc[4][4];
#pragma unroll
  for (int i = 0; i < 4; i++)
#pragma unroll
    for (int j = 0; j < 4; j++) acc[i][j] = (f32x4_t){0.f, 0.f, 0.f, 0.f};

  auto STAGE = [&](const int buf, const int k0) {
    const size_t kb = (size_t)k0 * 2;
    char* la = (char*)As + buf * 8192 + wave * 2048;
    char* lb = (char*)Bs + buf * 8192 + wave * 2048;
    gld16(ga0 + kb, la);
    gld16(ga1 + kb, la + 1024);
    gld16(gb0 + kb, lb);
    gld16(gb1 + kb, lb + 1024);
  };
  auto COMPUTE = [&](const int buf) {
    const char* AsB = (const char*)As + buf * 8192;
    const char* BsB = (const char*)Bs + buf * 8192;
    bf16x8_t af[4], bfr[4];
#pragma unroll
    for (int i = 0; i < 4; i++) {
      const int ao = aof0 + i * 1024;
      af[i] = mk_frag(*(const bf16x4_t*)(AsB + ao),
                      *(const bf16x4_t*)(AsB + (ao ^ 32)));
      const int bo = bof0 + i * 1024;
      bfr[i] = mk_frag(*(const bf16x4_t*)(BsB + bo),
                       *(const bf16x4_t*)(BsB + (bo ^ 32)));
    }
#pragma unroll
    for (int i = 0; i < 4; i++)
#pragma unroll
      for (int j = 0; j < 4; j++)
        acc[i][j] = __builtin_amdgcn_mfma_f32_16x16x32_bf16(af[i], bfr[j], acc[i][j], 0, 0, 0);
  };

  const int kend = CAUSAL ? (m0 + 128) : K;
  const int nt = kend >> 5;           // even for every call site (K % 64 == 0)
  STAGE(0, 0);
  __syncthreads();                    // buf0 resident
  for (int t = 0; t < nt; t += 2) {
    STAGE(1, (t + 1) << 5);           // prefetch while computing buf0
    COMPUTE(0);
    __syncthreads();                  // drain loads + all reads of buf0 done
    if (t + 2 < nt) STAGE(0, (t + 2) << 5);
    COMPUTE(1);
    __syncthreads();
  }

#pragma unroll
  for (int i = 0; i < 4; i++) {
#pragma unroll
    for (int j = 0; j < 4; j++) {
      const int col = n0 + wc * 64 + j * 16 + l15;
      if (QKV3) {
        const int sub = col >> 9, c5 = col & 511;   // sub uniform per block
        const float bv = (sub == 0 ? bias : sub == 1 ? bias2 : bias3)[c5];
        __bf16* cb = sub == 0 ? Cb : sub == 1 ? Cb2 : Cb3;
        float* cf = sub == 0 ? (float*)nullptr : sub == 1 ? Cf2 : Cf3;
#pragma unroll
        for (int r = 0; r < 4; r++) {
          const int row = m0 + wr * 64 + i * 16 + g * 4 + r;
          const float v = acc[i][j][r] + bv;
          cb[(size_t)row * DD + c5] = (__bf16)v;
          if (cf) cf[(size_t)row * DD + c5] = v;
        }
      } else {
        const float bv = bias ? bias[col] : 0.f;
#pragma unroll
        for (int r = 0; r < 4; r++) {
          const int row = m0 + wr * 64 + i * 16 + g * 4 + r;
          float v = acc[i][j][r];
          if (SCALE) v *= INVSQD;
          v += bv;
          if (RELU) v = fmaxf(v, 0.f);
          if (RES) v += (float)Res[(size_t)row * N + col];
          const size_t cidx = cOff + (size_t)row * N + col;
          if (Cb) Cb[cidx] = (__bf16)v;
          if (Cf) Cf[cidx] = v;
        }
      }
    }
  }
}

// ---------------- row softmax, in place on fp32 scores (lower-tri valid),
// writes normalized fp32 probs (exact zeros above diagonal) + bf16 copy.
__global__ __launch_bounds__(256) void softmax_kernel(
    float* __restrict__ att, __bf16* __restrict__ pb) {
  const int t = blockIdx.x * 4 + (threadIdx.x >> 6);   // global row (b*2048+q)
  const int gq = t & (SS - 1);                         // query index in batch
  const int lane = threadIdx.x & 63;
  float* row = att + (size_t)t * SS;
  __bf16* prow = pb + (size_t)t * SS;
  const int nch = (gq >> 9) + 1;   // 512-wide chunks containing valid cols
  float x[32];
  float m = -1e30f;
#pragma unroll
  for (int ch = 0; ch < 4; ch++) {
    float* xp = &x[ch * 8];
    if (ch < nch) {
      const int c0 = ch * 512 + lane * 8;
      float4 v0 = *(const float4*)(row + c0);
      float4 v1 = *(const float4*)(row + c0 + 4);
      xp[0]=v0.x; xp[1]=v0.y; xp[2]=v0.z; xp[3]=v0.w;
      xp[4]=v1.x; xp[5]=v1.y; xp[6]=v1.z; xp[7]=v1.w;
#pragma unroll
      for (int j = 0; j < 8; j++) {
        xp[j] = (c0 + j <= gq) ? xp[j] : -1e30f;  // select: immune to garbage
        m = fmaxf(m, xp[j]);
      }
    } else {
#pragma unroll
      for (int j = 0; j < 8; j++) xp[j] = -1e30f;
    }
  }
#pragma unroll
  for (int off = 1; off < 64; off <<= 1) m = fmaxf(m, __shfl_xor(m, off, 64));
  float s = 0.f;
#pragma unroll
  for (int i = 0; i < 32; i++) { x[i] = __expf(x[i] - m); s += x[i]; }
#pragma unroll
  for (int off = 1; off < 64; off <<= 1) s += __shfl_xor(s, off, 64);
  const float inv = 1.f / s;
#pragma unroll
  for (int ch = 0; ch < 4; ch++) {
    const int c0 = ch * 512 + lane * 8;
    float o[8];
    bf16x8_t ov;
#pragma unroll
    for (int j = 0; j < 8; j++) {
      const float pv = x[ch * 8 + j] * inv;  // masked entries exactly 0
      o[j] = pv;
      ov[j] = (__bf16)pv;
    }
    float4 f0, f1;
    f0.x = o[0]; f0.y = o[1]; f0.z = o[2]; f0.w = o[3];
    f1.x = o[4]; f1.y = o[5]; f1.z = o[6]; f1.w = o[7];
    *(float4*)(row + c0) = f0;
    *(float4*)(row + c0 + 4) = f1;
    *(bf16x8_t*)(prow + c0) = ov;
  }
}

// ---------------- LayerNorm over D=512 (population var, eps inside sqrt)
__global__ __launch_bounds__(256) void ln_kernel(
    const __bf16* __restrict__ X, const float* __restrict__ gam,
    const float* __restrict__ bet, __bf16* __restrict__ Ob, float* __restrict__ Of) {
  const int t = blockIdx.x * 4 + (threadIdx.x >> 6);
  const int lane = threadIdx.x & 63;
  const int d0 = lane * 8;
  bf16x8_t xv = *(const bf16x8_t*)(X + (size_t)t * DD + d0);
  float x[8];
#pragma unroll
  for (int j = 0; j < 8; j++) x[j] = (float)xv[j];
  float s = 0.f, sq = 0.f;
#pragma unroll
  for (int j = 0; j < 8; j++) { s += x[j]; sq += x[j] * x[j]; }
#pragma unroll
  for (int off = 1; off < 64; off <<= 1) {
    s += __shfl_xor(s, off, 64);
    sq += __shfl_xor(sq, off, 64);
  }
  const float mean = s * (1.f / 512.f);
  const float var = sq * (1.f / 512.f) - mean * mean;
  const float rstd = rsqrtf(var + 1e-6f);
  float4 g0 = *(const float4*)(gam + d0), g1v = *(const float4*)(gam + d0 + 4);
  float4 b0 = *(const float4*)(bet + d0), b1v = *(const float4*)(bet + d0 + 4);
  float gg[8] = {g0.x, g0.y, g0.z, g0.w, g1v.x, g1v.y, g1v.z, g1v.w};
  float bb2[8] = {b0.x, b0.y, b0.z, b0.w, b1v.x, b1v.y, b1v.z, b1v.w};
  float o[8];
#pragma unroll
  for (int j = 0; j < 8; j++) o[j] = (x[j] - mean) * rstd * gg[j] + bb2[j];
  if (Ob) {
    bf16x8_t ov;
#pragma unroll
    for (int j = 0; j < 8; j++) ov[j] = (__bf16)o[j];
    *(bf16x8_t*)(Ob + (size_t)t * DD + d0) = ov;
  }
  if (Of) {
    float4 f0; f0.x = o[0]; f0.y = o[1]; f0.z = o[2]; f0.w = o[3];
    float4 f1; f1.x = o[4]; f1.y = o[5]; f1.z = o[6]; f1.w = o[7];
    *(float4*)(Of + (size_t)t * DD + d0) = f0;
    *(float4*)(Of + (size_t)t * DD + d0 + 4) = f1;
  }
}

// ---------------- pred = r @ Wfin + bfin (K=512, N=16), written to both pred slots
__global__ __launch_bounds__(256) void final_kernel(
    const float* __restrict__ Rm, const float* __restrict__ Wfin,
    const float* __restrict__ bfin, float* __restrict__ P1, float* __restrict__ P2) {
  __shared__ float wfs[512][17];
  for (int i = threadIdx.x; i < 512 * 16; i += 256) wfs[i >> 4][i & 15] = Wfin[i];
  __syncthreads();
  const int tl = threadIdx.x >> 4, n = threadIdx.x & 15;
  const int t = blockIdx.x * 16 + tl;
  const float* rp = Rm + (size_t)t * DD;
  float acc = 0.f;
#pragma unroll 4
  for (int k = 0; k < 512; k += 4) {
    float4 rv = *(const float4*)(rp + k);
    acc += rv.x * wfs[k][n] + rv.y * wfs[k + 1][n] + rv.z * wfs[k + 2][n] + rv.w * wfs[k + 3][n];
  }
  const float v = acc + bfin[n];
  P1[(size_t)t * 16 + n] = v;
  P2[(size_t)t * 16 + n] = v;
}

extern "C" void kernel_launch(void* const* d_in, const int* in_sizes, int n_in,
                              void* d_out, int out_size, void* d_ws, size_t ws_size,
                              hipStream_t stream) {
  const float* inp  = (const float*)d_in[0];
  const float* Wp   = (const float*)d_in[2];
  const float* bp   = (const float*)d_in[3];
  const float* Wq   = (const float*)d_in[4];
  const float* bq   = (const float*)d_in[5];
  const float* Wk   = (const float*)d_in[6];
  const float* bk   = (const float*)d_in[7];
  const float* Wv   = (const float*)d_in[8];
  const float* bv   = (const float*)d_in[9];
  const float* Wo   = (const float*)d_in[10];
  const float* bo   = (const float*)d_in[11];
  const float* g1   = (const float*)d_in[12];
  const float* be1  = (const float*)d_in[13];
  const float* g2   = (const float*)d_in[14];
  const float* be2  = (const float*)d_in[15];
  const float* Wf1  = (const float*)d_in[16];
  const float* bf1  = (const float*)d_in[17];
  const float* Wf2  = (const float*)d_in[18];
  const float* bf2  = (const float*)d_in[19];
  const float* Wfin = (const float*)d_in[20];
  const float* bfin = (const float*)d_in[21];
  (void)in_sizes; (void)n_in; (void)out_size; (void)ws_size;

  float* out = (float*)d_out;
  float* o_pred1 = out;                    // (B,P,S,16)
  float* o_pred2 = out + 262144;
  float* o_k     = out + 524288;           // (B,P,S,512)
  float* o_v     = out + 8912896;
  float* o_r     = out + 17301504;
  float* o_att   = out + 25690112;         // (B,P,S,S)

  // workspace carve-up (~208 MB)
  char* base = (char*)d_ws;
  size_t off = 0;
  auto take = [&](size_t n) -> __bf16* {
    __bf16* p = (__bf16*)(base + off);
    off += (n * sizeof(__bf16) + 255) & ~(size_t)255;
    return p;
  };
  __bf16* Wqkv_t = take((size_t)3 * DD * DD);  // [1536][512]: q rows, k rows, v rows
  __bf16* Wo_t   = take((size_t)DD * DD);
  __bf16* Wf1_t  = take((size_t)DD * DFFX);
  __bf16* Wf2_t  = take((size_t)DD * DFFX);
  __bf16* xb     = take((size_t)TT * DD);
  __bf16* qbuf   = take((size_t)TT * DD);
  __bf16* kbuf   = take((size_t)TT * DD);
  __bf16* vbuf   = take((size_t)TT * DD);
  __bf16* zb     = take((size_t)TT * DD);
  __bf16* h1b    = take((size_t)TT * DD);
  __bf16* lninb  = take((size_t)TT * DD);
  __bf16* ffb    = take((size_t)TT * DFFX);
  __bf16* vt     = take((size_t)TT * DD);
  __bf16* pb     = ffb;  // bf16 probs alias FFN scratch (same element count;
                         // pb dead before FFN1 writes ffb)

  // weights -> bf16 transposed [N][K] (q/k/v stacked into Wqkv_t)
  transpose_conv_f32<<<dim3(16, 16), 256, 0, stream>>>(Wq, Wqkv_t, DD, DD);
  transpose_conv_f32<<<dim3(16, 16), 256, 0, stream>>>(Wk, Wqkv_t + (size_t)DD * DD, DD, DD);
  transpose_conv_f32<<<dim3(16, 16), 256, 0, stream>>>(Wv, Wqkv_t + (size_t)2 * DD * DD, DD, DD);
  transpose_conv_f32<<<dim3(16, 16), 256, 0, stream>>>(Wo, Wo_t, DD, DD);
  transpose_conv_f32<<<dim3(64, 16), 256, 0, stream>>>(Wf1, Wf1_t, DD, DFFX);
  transpose_conv_f32<<<dim3(16, 64), 256, 0, stream>>>(Wf2, Wf2_t, DFFX, DD);

  // x projection
  projx_kernel<<<dim3(TT / 4), 256, 0, stream>>>(inp, Wp, bp, xb);

  // fused q,k,v: one N=1536 GEMM (k,v also to fp32 outputs)
  gemm128<false, false, false, false, false, true><<<dim3(12, 128, 1), 256, 0, stream>>>(
      xb, Wqkv_t, bq, bk, bv, nullptr,
      qbuf, nullptr, kbuf, o_k, vbuf, o_v, 1536, DD, 0, 0, 0);

  // scores = q @ k^T / sqrt(d) -> fp32 into o_att (lower-triangle blocks only)
  gemm128<true, false, false, false, true, false><<<dim3(16, 16, BB), 256, 0, stream>>>(
      qbuf, kbuf, nullptr, nullptr, nullptr, nullptr,
      nullptr, o_att, nullptr, nullptr, nullptr, nullptr, SS, DD,
      (size_t)SS * DD, (size_t)SS * DD, (size_t)SS * SS);

  // v^T per batch (B-operand for PV)
  transpose_bf16<<<dim3(16, 64, BB), 256, 0, stream>>>(vbuf, vt, SS, DD);

  // softmax in place on o_att (fp32 probs, zeros above diag) + bf16 probs -> pb
  softmax_kernel<<<dim3(TT / 4), 256, 0, stream>>>(o_att, pb);

  // z = attn @ v (bf16 probs, causal k-tile skip)
  gemm128<false, true, false, false, false, false><<<dim3(4, 16, BB), 256, 0, stream>>>(
      pb, vt, nullptr, nullptr, nullptr, nullptr,
      zb, nullptr, nullptr, nullptr, nullptr, nullptr, DD, SS,
      (size_t)SS * SS, (size_t)DD * SS, (size_t)SS * DD);

  // O-proj + residual x, LN1
  gemm128<false, false, false, true, false, false><<<dim3(4, 128, 1), 256, 0, stream>>>(
      zb, Wo_t, bo, nullptr, nullptr, xb,
      lninb, nullptr, nullptr, nullptr, nullptr, nullptr, DD, DD, 0, 0, 0);
  ln_kernel<<<dim3(TT / 4), 256, 0, stream>>>(lninb, g1, be1, h1b, nullptr);

  // FFN (FFN1 overwrites ffb/pb — PV already done)
  gemm128<false, false, true, false, false, false><<<dim3(16, 128, 1), 256, 0, stream>>>(
      h1b, Wf1_t, bf1, nullptr, nullptr, nullptr,
      ffb, nullptr, nullptr, nullptr, nullptr, nullptr, DFFX, DD, 0, 0, 0);
  gemm128<false, false, false, true, false, false><<<dim3(4, 128, 1), 256, 0, stream>>>(
      ffb, Wf2_t, bf2, nullptr, nullptr, h1b,
      lninb, nullptr, nullptr, nullptr, nullptr, nullptr, DD, DFFX, 0, 0, 0);

  // LN2 -> r (fp32 output), final projection -> pred (written twice)
  ln_kernel<<<dim3(TT / 4), 256, 0, stream>>>(lninb, g2, be2, nullptr, o_r);
  final_kernel<<<dim3(TT / 16), 256, 0, stream>>>(o_r, Wfin, bfin, o_pred1, o_pred2);
}

// Round 5
// 508.421 us; speedup vs baseline: 1.0946x; 1.0472x over previous
//
#include <hip/hip_runtime.h>
#include <hip/hip_bf16.h>
#include <stdint.h>

// Problem dims (SMC transformer, noise=False => causal self-attention)
#define BB 8
#define SS 2048
#define TT (BB*SS)       // 16384 tokens total (P=1)
#define DD 512
#define DFFX 2048

static __device__ const float SQRTD  = 22.627416997969522f;   // sqrt(512)
static __device__ const float INVSQD = 0.04419417382415922f;  // 1/sqrt(512)

typedef __attribute__((ext_vector_type(4))) float  f32x4_t;
typedef __attribute__((ext_vector_type(8))) __bf16 bf16x8_t;
typedef __attribute__((ext_vector_type(4))) __bf16 bf16x4_t;

// MFMA 16x16x32 bf16 operand layout (gfx950), HW-verified rounds 1-4:
//   A: lane l, elem e -> A[l&15][4*(l>>4) + (e&3) + 16*(e>>2)]
//   B: lane l, elem e -> B[4*(l>>4) + (e&3) + 16*(e>>2)][l&15]
//   D: lane l, reg  r -> D[4*(l>>4) + r][l&15]
static __device__ __forceinline__ bf16x8_t mk_frag(bf16x4_t lo, bf16x4_t hi) {
  return __builtin_shufflevector(lo, hi, 0, 1, 2, 3, 4, 5, 6, 7);
}

// async global->LDS, 16B per lane, dest = uniform base + lane*16
typedef __attribute__((address_space(1))) const unsigned int g_u32;
typedef __attribute__((address_space(3))) unsigned int lds_u32;
static __device__ __forceinline__ void gld16(const void* g, void* l) {
  __builtin_amdgcn_global_load_lds((g_u32*)g, (lds_u32*)l, 16, 0, 0);
}

// ---------------- weight transpose + convert: dst[C][R] (bf16) = src[R][C] (f32)
__global__ __launch_bounds__(256) void transpose_conv_f32(
    const float* __restrict__ src, __bf16* __restrict__ dst, int R, int C) {
  __shared__ float tile[32][33];
  int c0 = blockIdx.x * 32, r0 = blockIdx.y * 32;
  int tx = threadIdx.x & 31, ty = threadIdx.x >> 5;
#pragma unroll
  for (int i = 0; i < 4; i++)
    tile[ty + 8*i][tx] = src[(size_t)(r0 + ty + 8*i) * C + c0 + tx];
  __syncthreads();
#pragma unroll
  for (int i = 0; i < 4; i++)
    dst[(size_t)(c0 + ty + 8*i) * R + r0 + tx] = (__bf16)tile[tx][ty + 8*i];
}

// ---------------- per-batch bf16 transpose: dst[z][C][R] = src[z][R][C]
__global__ __launch_bounds__(256) void transpose_bf16(
    const __bf16* __restrict__ src_, __bf16* __restrict__ dst_, int R, int C) {
  __shared__ __bf16 tile[32][34];
  const __bf16* src = src_ + (size_t)blockIdx.z * R * C;
  __bf16* dst = dst_ + (size_t)blockIdx.z * R * C;
  int c0 = blockIdx.x * 32, r0 = blockIdx.y * 32;
  int tx = threadIdx.x & 31, ty = threadIdx.x >> 5;
#pragma unroll
  for (int i = 0; i < 4; i++)
    tile[ty + 8*i][tx] = src[(size_t)(r0 + ty + 8*i) * C + c0 + tx];
  __syncthreads();
#pragma unroll
  for (int i = 0; i < 4; i++)
    dst[(size_t)(c0 + ty + 8*i) * R + r0 + tx] = tile[tx][ty + 8*i];
}

// ---------------- x = (inp @ Wp + bp) * sqrt(D), K=16, out bf16
__global__ __launch_bounds__(256) void projx_kernel(
    const float* __restrict__ inp, const float* __restrict__ Wp,
    const float* __restrict__ bp, __bf16* __restrict__ xb) {
  __shared__ float wps[16][512];
  for (int i = threadIdx.x; i < 16 * 512; i += 256) wps[i >> 9][i & 511] = Wp[i];
  __syncthreads();
  const int t = blockIdx.x * 4 + (threadIdx.x >> 6);
  const int li = threadIdx.x & 63;
  float iv[16];
#pragma unroll
  for (int r = 0; r < 16; r++) iv[r] = inp[(size_t)t * 16 + r];
  float acc[8];
#pragma unroll
  for (int j = 0; j < 8; j++) acc[j] = 0.f;
#pragma unroll
  for (int r = 0; r < 16; r++) {
#pragma unroll
    for (int j = 0; j < 8; j++) acc[j] += iv[r] * wps[r][li + 64 * j];
  }
#pragma unroll
  for (int j = 0; j < 8; j++) {
    int c = li + 64 * j;
    xb[(size_t)t * DD + c] = (__bf16)((acc[j] + bp[c]) * SQRTD);
  }
}

// ---------------- 128x128-tile MFMA GEMM, 3-buffer ring + counted vmcnt (T4):
// prologue stages tiles 0..2 (12 loads/wave in flight). Each K-step:
//   s_waitcnt vmcnt(8)  -> oldest tile's 4 loads retired (FIFO, m135)
//   s_barrier           -> tile visible to all waves
//   COMPUTE             -> ds_read frags + 16 MFMA
//   s_barrier           -> all waves done reading this buf
//   STAGE(t+3) into it  -> loads get ~2 compute phases to land
// Tail waits vmcnt(4)/vmcnt(0). Never a full drain in steady state.
// Staging via global_load_lds(16B) into linear LDS with XOR chunk swizzle on
// the global SOURCE and the ds_read addresses (both-sides involution).
// CTRI: skip blocks with n0 > m0+127.  CAUSAL: k-loop ends at m0+128 (PV).
// RELU: relu(acc+bias).  RES: += Res.  SCALE: acc *= 1/sqrt(D).
// QKV3: N=1536 fused q/k/v; output segment sub = col>>9 (block-uniform) routes
// to {Cb|Cb2+Cf2|Cb3+Cf3} with bias {bias|bias2|bias3}, ldc=512.
template <bool CTRI, bool CAUSAL, bool RELU, bool RES, bool SCALE, bool QKV3>
__global__ __launch_bounds__(256) void gemm128(
    const __bf16* __restrict__ A, const __bf16* __restrict__ Bt,
    const float* __restrict__ bias, const float* __restrict__ bias2,
    const float* __restrict__ bias3, const __bf16* __restrict__ Res,
    __bf16* __restrict__ Cb, float* __restrict__ Cf,
    __bf16* __restrict__ Cb2, float* __restrict__ Cf2,
    __bf16* __restrict__ Cb3, float* __restrict__ Cf3,
    int N, int K, size_t aBatch, size_t bBatch, size_t cBatch) {
  const int n0 = blockIdx.x * 128, m0 = blockIdx.y * 128;
  if (CTRI && n0 > m0 + 127) return;
  __shared__ __align__(16) __bf16 As[3 * 128 * 32];   // 3 x 8 KB
  __shared__ __align__(16) __bf16 Bs[3 * 128 * 32];
  const int tid = threadIdx.x, lane = tid & 63, wave = tid >> 6;
  const int l15 = lane & 15, g = lane >> 4;
  const int wr = wave >> 1, wc = wave & 1;

  // ---- staging decode: lane's LDS slot = buf*8192 + wave*2048 + lane*16 B.
  // row = wave*32 + q*16 + (lane>>2); physical chunk = lane&3;
  // source logical chunk = (lane&3) ^ ((row>>1)&3)  (XOR involution)
  const int srow0 = wave * 32 + (lane >> 2);
  const int srow1 = srow0 + 16;
  const int sc0 = (((lane & 3) ^ ((srow0 >> 1) & 3)) << 4);
  const int sc1 = (((lane & 3) ^ ((srow1 >> 1) & 3)) << 4);
  const size_t aOff = (size_t)blockIdx.z * aBatch;
  const size_t bOff = (size_t)blockIdx.z * bBatch;
  const size_t cOff = (size_t)blockIdx.z * cBatch;
  const char* ga0 = (const char*)(A + aOff + (size_t)(m0 + srow0) * K) + sc0;
  const char* ga1 = (const char*)(A + aOff + (size_t)(m0 + srow1) * K) + sc1;
  const char* gb0 = (const char*)(Bt + bOff + (size_t)(n0 + srow0) * K) + sc0;
  const char* gb1 = (const char*)(Bt + bOff + (size_t)(n0 + srow1) * K) + sc1;

  // ---- frag-read byte offsets (linear+swizzled LDS):
  // physical chunk = logical ^ ((l15>>1)&3); hi half = lo addr ^ 32.
  const int plo = (g >> 1) ^ ((l15 >> 1) & 3);
  const int aof0 = (wr * 64 + l15) * 64 + plo * 16 + (g & 1) * 8;
  const int bof0 = (wc * 64 + l15) * 64 + plo * 16 + (g & 1) * 8;

  f32x4_t acc[4][4];
#pragma unroll
  for (int i = 0; i < 4; i++)
#pragma unroll
    for (int j = 0; j < 4; j++) acc[i][j] = (f32x4_t){0.f, 0.f, 0.f, 0.f};

  auto STAGE = [&](const int buf, const int k0) {
    const size_t kb = (size_t)k0 * 2;
    char* la = (char*)As + buf * 8192 + wave * 2048;
    char* lb = (char*)Bs + buf * 8192 + wave * 2048;
    gld16(ga0 + kb, la);
    gld16(ga1 + kb, la + 1024);
    gld16(gb0 + kb, lb);
    gld16(gb1 + kb, lb + 1024);
  };
  auto COMPUTE = [&](const int buf) {
    const char* AsB = (const char*)As + buf * 8192;
    const char* BsB = (const char*)Bs + buf * 8192;
    bf16x8_t af[4], bfr[4];
#pragma unroll
    for (int i = 0; i < 4; i++) {
      const int ao = aof0 + i * 1024;
      af[i] = mk_frag(*(const bf16x4_t*)(AsB + ao),
                      *(const bf16x4_t*)(AsB + (ao ^ 32)));
      const int bo = bof0 + i * 1024;
      bfr[i] = mk_frag(*(const bf16x4_t*)(BsB + bo),
                       *(const bf16x4_t*)(BsB + (bo ^ 32)));
    }
#pragma unroll
    for (int i = 0; i < 4; i++)
#pragma unroll
      for (int j = 0; j < 4; j++)
        acc[i][j] = __builtin_amdgcn_mfma_f32_16x16x32_bf16(af[i], bfr[j], acc[i][j], 0, 0, 0);
  };

  const int kend = CAUSAL ? (m0 + 128) : K;
  const int nt = kend >> 5;           // >= 4 at every call site
  STAGE(0, 0);
  STAGE(1, 32);
  STAGE(2, 64);
  int cur = 0;
  for (int t = 0; t < nt; ++t) {
    const int rem = nt - 1 - t;
    if (rem >= 2)      asm volatile("s_waitcnt vmcnt(8)" ::: "memory");
    else if (rem == 1) asm volatile("s_waitcnt vmcnt(4)" ::: "memory");
    else               asm volatile("s_waitcnt vmcnt(0)" ::: "memory");
    __builtin_amdgcn_s_barrier();     // tile t visible everywhere
    COMPUTE(cur);
    __builtin_amdgcn_s_barrier();     // all reads of buf `cur` done
    if (t + 3 < nt) STAGE(cur, (t + 3) << 5);
    cur = (cur == 2) ? 0 : cur + 1;
  }

#pragma unroll
  for (int i = 0; i < 4; i++) {
#pragma unroll
    for (int j = 0; j < 4; j++) {
      const int col = n0 + wc * 64 + j * 16 + l15;
      if (QKV3) {
        const int sub = col >> 9, c5 = col & 511;   // sub uniform per block
        const float bv = (sub == 0 ? bias : sub == 1 ? bias2 : bias3)[c5];
        __bf16* cb = sub == 0 ? Cb : sub == 1 ? Cb2 : Cb3;
        float* cf = sub == 0 ? (float*)nullptr : sub == 1 ? Cf2 : Cf3;
#pragma unroll
        for (int r = 0; r < 4; r++) {
          const int row = m0 + wr * 64 + i * 16 + g * 4 + r;
          const float v = acc[i][j][r] + bv;
          cb[(size_t)row * DD + c5] = (__bf16)v;
          if (cf) cf[(size_t)row * DD + c5] = v;
        }
      } else {
        const float bv = bias ? bias[col] : 0.f;
#pragma unroll
        for (int r = 0; r < 4; r++) {
          const int row = m0 + wr * 64 + i * 16 + g * 4 + r;
          float v = acc[i][j][r];
          if (SCALE) v *= INVSQD;
          v += bv;
          if (RELU) v = fmaxf(v, 0.f);
          if (RES) v += (float)Res[(size_t)row * N + col];
          const size_t cidx = cOff + (size_t)row * N + col;
          if (Cb) Cb[cidx] = (__bf16)v;
          if (Cf) Cf[cidx] = v;
        }
      }
    }
  }
}

// ---------------- row softmax, in place on fp32 scores (lower-tri valid),
// writes normalized fp32 probs (exact zeros above diagonal) + bf16 copy.
__global__ __launch_bounds__(256) void softmax_kernel(
    float* __restrict__ att, __bf16* __restrict__ pb) {
  const int t = blockIdx.x * 4 + (threadIdx.x >> 6);   // global row (b*2048+q)
  const int gq = t & (SS - 1);                         // query index in batch
  const int lane = threadIdx.x & 63;
  float* row = att + (size_t)t * SS;
  __bf16* prow = pb + (size_t)t * SS;
  const int nch = (gq >> 9) + 1;   // 512-wide chunks containing valid cols
  float x[32];
  float m = -1e30f;
#pragma unroll
  for (int ch = 0; ch < 4; ch++) {
    float* xp = &x[ch * 8];
    if (ch < nch) {
      const int c0 = ch * 512 + lane * 8;
      float4 v0 = *(const float4*)(row + c0);
      float4 v1 = *(const float4*)(row + c0 + 4);
      xp[0]=v0.x; xp[1]=v0.y; xp[2]=v0.z; xp[3]=v0.w;
      xp[4]=v1.x; xp[5]=v1.y; xp[6]=v1.z; xp[7]=v1.w;
#pragma unroll
      for (int j = 0; j < 8; j++) {
        xp[j] = (c0 + j <= gq) ? xp[j] : -1e30f;  // select: immune to garbage
        m = fmaxf(m, xp[j]);
      }
    } else {
#pragma unroll
      for (int j = 0; j < 8; j++) xp[j] = -1e30f;
    }
  }
#pragma unroll
  for (int off = 1; off < 64; off <<= 1) m = fmaxf(m, __shfl_xor(m, off, 64));
  float s = 0.f;
#pragma unroll
  for (int i = 0; i < 32; i++) { x[i] = __expf(x[i] - m); s += x[i]; }
#pragma unroll
  for (int off = 1; off < 64; off <<= 1) s += __shfl_xor(s, off, 64);
  const float inv = 1.f / s;
#pragma unroll
  for (int ch = 0; ch < 4; ch++) {
    const int c0 = ch * 512 + lane * 8;
    float o[8];
    bf16x8_t ov;
#pragma unroll
    for (int j = 0; j < 8; j++) {
      const float pv = x[ch * 8 + j] * inv;  // masked entries exactly 0
      o[j] = pv;
      ov[j] = (__bf16)pv;
    }
    float4 f0, f1;
    f0.x = o[0]; f0.y = o[1]; f0.z = o[2]; f0.w = o[3];
    f1.x = o[4]; f1.y = o[5]; f1.z = o[6]; f1.w = o[7];
    *(float4*)(row + c0) = f0;
    *(float4*)(row + c0 + 4) = f1;
    *(bf16x8_t*)(prow + c0) = ov;
  }
}

// ---------------- LayerNorm over D=512 (population var, eps inside sqrt)
__global__ __launch_bounds__(256) void ln_kernel(
    const __bf16* __restrict__ X, const float* __restrict__ gam,
    const float* __restrict__ bet, __bf16* __restrict__ Ob, float* __restrict__ Of) {
  const int t = blockIdx.x * 4 + (threadIdx.x >> 6);
  const int lane = threadIdx.x & 63;
  const int d0 = lane * 8;
  bf16x8_t xv = *(const bf16x8_t*)(X + (size_t)t * DD + d0);
  float x[8];
#pragma unroll
  for (int j = 0; j < 8; j++) x[j] = (float)xv[j];
  float s = 0.f, sq = 0.f;
#pragma unroll
  for (int j = 0; j < 8; j++) { s += x[j]; sq += x[j] * x[j]; }
#pragma unroll
  for (int off = 1; off < 64; off <<= 1) {
    s += __shfl_xor(s, off, 64);
    sq += __shfl_xor(sq, off, 64);
  }
  const float mean = s * (1.f / 512.f);
  const float var = sq * (1.f / 512.f) - mean * mean;
  const float rstd = rsqrtf(var + 1e-6f);
  float4 g0 = *(const float4*)(gam + d0), g1v = *(const float4*)(gam + d0 + 4);
  float4 b0 = *(const float4*)(bet + d0), b1v = *(const float4*)(bet + d0 + 4);
  float gg[8] = {g0.x, g0.y, g0.z, g0.w, g1v.x, g1v.y, g1v.z, g1v.w};
  float bb2[8] = {b0.x, b0.y, b0.z, b0.w, b1v.x, b1v.y, b1v.z, b1v.w};
  float o[8];
#pragma unroll
  for (int j = 0; j < 8; j++) o[j] = (x[j] - mean) * rstd * gg[j] + bb2[j];
  if (Ob) {
    bf16x8_t ov;
#pragma unroll
    for (int j = 0; j < 8; j++) ov[j] = (__bf16)o[j];
    *(bf16x8_t*)(Ob + (size_t)t * DD + d0) = ov;
  }
  if (Of) {
    float4 f0; f0.x = o[0]; f0.y = o[1]; f0.z = o[2]; f0.w = o[3];
    float4 f1; f1.x = o[4]; f1.y = o[5]; f1.z = o[6]; f1.w = o[7];
    *(float4*)(Of + (size_t)t * DD + d0) = f0;
    *(float4*)(Of + (size_t)t * DD + d0 + 4) = f1;
  }
}

// ---------------- pred = r @ Wfin + bfin (K=512, N=16), written to both pred slots
__global__ __launch_bounds__(256) void final_kernel(
    const float* __restrict__ Rm, const float* __restrict__ Wfin,
    const float* __restrict__ bfin, float* __restrict__ P1, float* __restrict__ P2) {
  __shared__ float wfs[512][17];
  for (int i = threadIdx.x; i < 512 * 16; i += 256) wfs[i >> 4][i & 15] = Wfin[i];
  __syncthreads();
  const int tl = threadIdx.x >> 4, n = threadIdx.x & 15;
  const int t = blockIdx.x * 16 + tl;
  const float* rp = Rm + (size_t)t * DD;
  float acc = 0.f;
#pragma unroll 4
  for (int k = 0; k < 512; k += 4) {
    float4 rv = *(const float4*)(rp + k);
    acc += rv.x * wfs[k][n] + rv.y * wfs[k + 1][n] + rv.z * wfs[k + 2][n] + rv.w * wfs[k + 3][n];
  }
  const float v = acc + bfin[n];
  P1[(size_t)t * 16 + n] = v;
  P2[(size_t)t * 16 + n] = v;
}

extern "C" void kernel_launch(void* const* d_in, const int* in_sizes, int n_in,
                              void* d_out, int out_size, void* d_ws, size_t ws_size,
                              hipStream_t stream) {
  const float* inp  = (const float*)d_in[0];
  const float* Wp   = (const float*)d_in[2];
  const float* bp   = (const float*)d_in[3];
  const float* Wq   = (const float*)d_in[4];
  const float* bq   = (const float*)d_in[5];
  const float* Wk   = (const float*)d_in[6];
  const float* bk   = (const float*)d_in[7];
  const float* Wv   = (const float*)d_in[8];
  const float* bv   = (const float*)d_in[9];
  const float* Wo   = (const float*)d_in[10];
  const float* bo   = (const float*)d_in[11];
  const float* g1   = (const float*)d_in[12];
  const float* be1  = (const float*)d_in[13];
  const float* g2   = (const float*)d_in[14];
  const float* be2  = (const float*)d_in[15];
  const float* Wf1  = (const float*)d_in[16];
  const float* bf1  = (const float*)d_in[17];
  const float* Wf2  = (const float*)d_in[18];
  const float* bf2  = (const float*)d_in[19];
  const float* Wfin = (const float*)d_in[20];
  const float* bfin = (const float*)d_in[21];
  (void)in_sizes; (void)n_in; (void)out_size; (void)ws_size;

  float* out = (float*)d_out;
  float* o_pred1 = out;                    // (B,P,S,16)
  float* o_pred2 = out + 262144;
  float* o_k     = out + 524288;           // (B,P,S,512)
  float* o_v     = out + 8912896;
  float* o_r     = out + 17301504;
  float* o_att   = out + 25690112;         // (B,P,S,S)

  // workspace carve-up (~208 MB)
  char* base = (char*)d_ws;
  size_t off = 0;
  auto take = [&](size_t n) -> __bf16* {
    __bf16* p = (__bf16*)(base + off);
    off += (n * sizeof(__bf16) + 255) & ~(size_t)255;
    return p;
  };
  __bf16* Wqkv_t = take((size_t)3 * DD * DD);  // [1536][512]: q rows, k rows, v rows
  __bf16* Wo_t   = take((size_t)DD * DD);
  __bf16* Wf1_t  = take((size_t)DD * DFFX);
  __bf16* Wf2_t  = take((size_t)DD * DFFX);
  __bf16* xb     = take((size_t)TT * DD);
  __bf16* qbuf   = take((size_t)TT * DD);
  __bf16* kbuf   = take((size_t)TT * DD);
  __bf16* vbuf   = take((size_t)TT * DD);
  __bf16* zb     = take((size_t)TT * DD);
  __bf16* h1b    = take((size_t)TT * DD);
  __bf16* lninb  = take((size_t)TT * DD);
  __bf16* ffb    = take((size_t)TT * DFFX);
  __bf16* vt     = take((size_t)TT * DD);
  __bf16* pb     = ffb;  // bf16 probs alias FFN scratch (same element count;
                         // pb dead before FFN1 writes ffb)

  // weights -> bf16 transposed [N][K] (q/k/v stacked into Wqkv_t)
  transpose_conv_f32<<<dim3(16, 16), 256, 0, stream>>>(Wq, Wqkv_t, DD, DD);
  transpose_conv_f32<<<dim3(16, 16), 256, 0, stream>>>(Wk, Wqkv_t + (size_t)DD * DD, DD, DD);
  transpose_conv_f32<<<dim3(16, 16), 256, 0, stream>>>(Wv, Wqkv_t + (size_t)2 * DD * DD, DD, DD);
  transpose_conv_f32<<<dim3(16, 16), 256, 0, stream>>>(Wo, Wo_t, DD, DD);
  transpose_conv_f32<<<dim3(64, 16), 256, 0, stream>>>(Wf1, Wf1_t, DD, DFFX);
  transpose_conv_f32<<<dim3(16, 64), 256, 0, stream>>>(Wf2, Wf2_t, DFFX, DD);

  // x projection
  projx_kernel<<<dim3(TT / 4), 256, 0, stream>>>(inp, Wp, bp, xb);

  // fused q,k,v: one N=1536 GEMM (k,v also to fp32 outputs)
  gemm128<false, false, false, false, false, true><<<dim3(12, 128, 1), 256, 0, stream>>>(
      xb, Wqkv_t, bq, bk, bv, nullptr,
      qbuf, nullptr, kbuf, o_k, vbuf, o_v, 1536, DD, 0, 0, 0);

  // scores = q @ k^T / sqrt(d) -> fp32 into o_att (lower-triangle blocks only)
  gemm128<true, false, false, false, true, false><<<dim3(16, 16, BB), 256, 0, stream>>>(
      qbuf, kbuf, nullptr, nullptr, nullptr, nullptr,
      nullptr, o_att, nullptr, nullptr, nullptr, nullptr, SS, DD,
      (size_t)SS * DD, (size_t)SS * DD, (size_t)SS * SS);

  // v^T per batch (B-operand for PV)
  transpose_bf16<<<dim3(16, 64, BB), 256, 0, stream>>>(vbuf, vt, SS, DD);

  // softmax in place on o_att (fp32 probs, zeros above diag) + bf16 probs -> pb
  softmax_kernel<<<dim3(TT / 4), 256, 0, stream>>>(o_att, pb);

  // z = attn @ v (bf16 probs, causal k-tile skip)
  gemm128<false, true, false, false, false, false><<<dim3(4, 16, BB), 256, 0, stream>>>(
      pb, vt, nullptr, nullptr, nullptr, nullptr,
      zb, nullptr, nullptr, nullptr, nullptr, nullptr, DD, SS,
      (size_t)SS * SS, (size_t)DD * SS, (size_t)SS * DD);

  // O-proj + residual x, LN1
  gemm128<false, false, false, true, false, false><<<dim3(4, 128, 1), 256, 0, stream>>>(
      zb, Wo_t, bo, nullptr, nullptr, xb,
      lninb, nullptr, nullptr, nullptr, nullptr, nullptr, DD, DD, 0, 0, 0);
  ln_kernel<<<dim3(TT / 4), 256, 0, stream>>>(lninb, g1, be1, h1b, nullptr);

  // FFN (FFN1 overwrites ffb/pb — PV already done)
  gemm128<false, false, true, false, false, false><<<dim3(16, 128, 1), 256, 0, stream>>>(
      h1b, Wf1_t, bf1, nullptr, nullptr, nullptr,
      ffb, nullptr, nullptr, nullptr, nullptr, nullptr, DFFX, DD, 0, 0, 0);
  gemm128<false, false, false, true, false, false><<<dim3(4, 128, 1), 256, 0, stream>>>(
      ffb, Wf2_t, bf2, nullptr, nullptr, h1b,
      lninb, nullptr, nullptr, nullptr, nullptr, nullptr, DD, DFFX, 0, 0, 0);

  // LN2 -> r (fp32 output), final projection -> pred (written twice)
  ln_kernel<<<dim3(TT / 4), 256, 0, stream>>>(lninb, g2, be2, nullptr, o_r);
  final_kernel<<<dim3(TT / 16), 256, 0, stream>>>(o_r, Wfin, bfin, o_pred1, o_pred2);
}